// Round 1
// baseline (1951.679 us; speedup 1.0000x reference)
//
#include <hip/hip_runtime.h>
#include <cstddef>

#define NB 64
#define LL 512
#define HH 256
#define HD 128
#define TI 16
#define NP 19   // TI + 3 window positions

__device__ __forceinline__ float sigm(float x)  { return 1.0f / (1.0f + __expf(-x)); }
__device__ __forceinline__ float tanhf_(float x){ return 2.0f / (1.0f + __expf(-2.0f * x)) - 1.0f; }

__global__ __launch_bounds__(256, 2) void fused_span_lstm(
    const float* __restrict__ feats, const float* __restrict__ W_ih,
    const float* __restrict__ W_hh, const float* __restrict__ b_ih,
    const float* __restrict__ b_hh, const float* __restrict__ W_tri,
    const float* __restrict__ b_tri, const int* __restrict__ lens,
    float* __restrict__ out)
{
    // LDS: 20*256*4 + 20*512*4 + 16*128*4 = 20480 + 40960 + 8192 = 69632 B -> 2 blocks/CU
    __shared__ __align__(16) float sFeat[NP + 1][HH];
    __shared__ __align__(16) float sXG[NP + 1][4 * HD];
    __shared__ __align__(16) float sH[TI][HD];

    const int tid = threadIdx.x;
    const int b  = blockIdx.x >> 5;          // 32 tiles per batch row
    const int i0 = (blockIdx.x & 31) * TI;
    const int lens_b = lens[b];

    // ---- stage feats window (zero-pad past LL). Row 19 is a pad row (loaded, never used). ----
    for (int idx = tid; idx < (NP + 1) * HH; idx += 256) {
        const int p = idx >> 8;
        const int k = idx & (HH - 1);
        const int gp = i0 + p;
        sFeat[p][k] = (gp < LL) ? feats[((size_t)b * LL + gp) * HH + k] : 0.0f;
    }
    for (int idx = tid; idx < TI * HD; idx += 256) ((float*)sH)[idx] = 0.0f;
    __syncthreads();

    // ---- phase 1: sXG[p][g] = b_ih[g] + b_hh[g] + sum_k sFeat[p][k] * W_ih[g][k]
    // thread -> 8 consecutive gate rows (g0..g0+7), 5 positions. pq is wave-uniform,
    // so the sFeat float4 read is a broadcast (conflict-free).
    {
        const int g0 = (tid & 63) * 8;
        const int pb = (tid >> 6) * 5;       // 0,5,10,15 ; pb=15 covers p=15..19 (19 = pad)
        float acc[5][8];
        #pragma unroll
        for (int pi = 0; pi < 5; ++pi)
            #pragma unroll
            for (int gi = 0; gi < 8; ++gi) acc[pi][gi] = 0.0f;

        for (int kk = 0; kk < HH; kk += 4) {
            float4 wv[8];
            #pragma unroll
            for (int gi = 0; gi < 8; ++gi)
                wv[gi] = *(const float4*)(W_ih + (size_t)(g0 + gi) * HH + kk);
            #pragma unroll
            for (int pi = 0; pi < 5; ++pi) {
                const float4 f = *(const float4*)(&sFeat[pb + pi][kk]);
                #pragma unroll
                for (int gi = 0; gi < 8; ++gi)
                    acc[pi][gi] += wv[gi].x * f.x + wv[gi].y * f.y
                                 + wv[gi].z * f.z + wv[gi].w * f.w;
            }
        }
        float bsum[8];
        #pragma unroll
        for (int gi = 0; gi < 8; ++gi) bsum[gi] = b_ih[g0 + gi] + b_hh[g0 + gi];
        #pragma unroll
        for (int pi = 0; pi < 5; ++pi)
            #pragma unroll
            for (int gi = 0; gi < 8; ++gi)
                sXG[pb + pi][g0 + gi] = acc[pi][gi] + bsum[gi];
    }
    __syncthreads();

    // ---- phase 2: 4-step recurrence. thread t owns hidden unit j = t&127 for 8 seqs.
    // sH float4 reads are wave-uniform broadcasts; W_hh rows differ per lane (L1-resident walk).
    const int j  = tid & (HD - 1);
    const int sg = tid >> 7;                 // 0 or 1 -> sequences sg*8 .. sg*8+7
    float c[8];
    #pragma unroll
    for (int si = 0; si < 8; ++si) c[si] = 0.0f;

    for (int t = 0; t < 4; ++t) {
        float acc2[8][4];
        #pragma unroll
        for (int si = 0; si < 8; ++si) {
            const int s = sg * 8 + si;
            #pragma unroll
            for (int g = 0; g < 4; ++g)
                acc2[si][g] = sXG[s + t][g * HD + j];   // torch gate order i,f,g,o
        }
        for (int kk = 0; kk < HD; kk += 4) {
            float4 wv[4];
            #pragma unroll
            for (int g = 0; g < 4; ++g)
                wv[g] = *(const float4*)(W_hh + (size_t)(g * HD + j) * HD + kk);
            #pragma unroll
            for (int si = 0; si < 8; ++si) {
                const float4 hv = *(const float4*)(&sH[sg * 8 + si][kk]);
                #pragma unroll
                for (int g = 0; g < 4; ++g)
                    acc2[si][g] += wv[g].x * hv.x + wv[g].y * hv.y
                                 + wv[g].z * hv.z + wv[g].w * hv.w;
            }
        }
        __syncthreads();   // all reads of old sH complete before overwrite

        float hnew[8];
        #pragma unroll
        for (int si = 0; si < 8; ++si) {
            const float ig = sigm(acc2[si][0]);
            const float fg = sigm(acc2[si][1]);
            const float gg = tanhf_(acc2[si][2]);
            const float og = sigm(acc2[si][3]);
            c[si]   = fg * c[si] + ig * gg;
            hnew[si] = og * tanhf_(c[si]);
        }
        #pragma unroll
        for (int si = 0; si < 8; ++si) sH[sg * 8 + si][j] = hnew[si];
        __syncthreads();   // new sH visible to everyone

        // ---- fused emission: spans whose selected step == t+1 write now.
        // s_w = clamp(lens-i, 1, w). If sc < rem: only w=sc. If sc == rem (or sc==min(rem,4)
        // with rem>=4): widths sc..4 all use this h.
        if (tid < 32) {
            const int s = tid >> 1, tag = tid & 1;
            const int i = i0 + s;
            const int rem = lens_b - i;
            const int sc = t + 1;
            if (rem > 0 && sc <= rem) {
                float ex = 0.f, ey = 0.f, ez = 0.f, ew = 0.f;
                for (int kk = 0; kk < HD; kk += 4) {
                    const float4 hv = *(const float4*)(&sH[s][kk]);
                    const float4 wt = *(const float4*)(W_tri + (size_t)tag * HD + kk);
                    ex += hv.x * wt.x; ey += hv.y * wt.y;
                    ez += hv.z * wt.z; ew += hv.w * wt.w;
                }
                const float e = (ex + ey) + (ez + ew) + b_tri[tag];
                const int m   = rem < 4 ? rem : 4;
                const int whi = (sc >= m) ? 4 : sc;
                for (int w = sc; w <= whi; ++w) {
                    const int jj = i + w - 1;
                    if (jj < LL)
                        out[(((size_t)b * LL + i) * LL + jj) * 2 + tag] = e;
                }
            }
        }
    }
}

extern "C" void kernel_launch(void* const* d_in, const int* in_sizes, int n_in,
                              void* d_out, int out_size, void* d_ws, size_t ws_size,
                              hipStream_t stream)
{
    const float* feats = (const float*)d_in[0];
    const float* W_ih  = (const float*)d_in[1];
    const float* W_hh  = (const float*)d_in[2];
    const float* b_ih  = (const float*)d_in[3];
    const float* b_hh  = (const float*)d_in[4];
    const float* W_tri = (const float*)d_in[5];
    const float* b_tri = (const float*)d_in[6];
    const int*   lens  = (const int*)d_in[7];
    float* out = (float*)d_out;

    hipMemsetAsync(out, 0, (size_t)out_size * sizeof(float), stream);

    dim3 grid(NB * (LL / TI));   // 2048 blocks
    fused_span_lstm<<<grid, 256, 0, stream>>>(feats, W_ih, W_hh, b_ih, b_hh,
                                              W_tri, b_tri, lens, out);
}

// Round 2
// 664.143 us; speedup vs baseline: 2.9386x; 2.9386x over previous
//
#include <hip/hip_runtime.h>
#include <cstddef>

#define NB 64
#define LL 512
#define HH 256
#define HD 128
#define NG 512
#define TI 16
#define NP 20   // 19 used positions + 1 pad row

__device__ __forceinline__ float sigm(float x)  { return 1.0f / (1.0f + __expf(-x)); }
__device__ __forceinline__ float tanhf_(float x){ return 2.0f / (1.0f + __expf(-2.0f * x)) - 1.0f; }

// ---------------- weight transpose: WT[k][g] = W[g][k] (coalesced writes) ----------------
__global__ void transpose_w(const float* __restrict__ Wih, const float* __restrict__ Whh,
                            float* __restrict__ WihT, float* __restrict__ WhhT)
{
    int idx = blockIdx.x * 256 + threadIdx.x;
    if (idx < NG * HH) {                       // WihT: [256][512]
        const int k = idx >> 9, g = idx & 511;
        WihT[idx] = Wih[(size_t)g * HH + k];
    }
    idx -= NG * HH;
    if (idx >= 0 && idx < NG * HD) {           // WhhT: [128][512]
        const int k = idx >> 9, g = idx & 511;
        WhhT[idx] = Whh[(size_t)g * HD + k];
    }
}

// ---------------- main fused kernel (v2: gate-contiguous weight streams) ----------------
__global__ __launch_bounds__(256, 2) void span_lstm_v2(
    const float* __restrict__ feats, const float* __restrict__ WihT,
    const float* __restrict__ WhhT, const float* __restrict__ b_ih,
    const float* __restrict__ b_hh, const float* __restrict__ W_tri,
    const float* __restrict__ b_tri, const int* __restrict__ lens,
    float* __restrict__ out)
{
    // 41600 + 20800 + 8448 + 256 = 71104 B -> 2 blocks/CU
    __shared__ __align__(16) float sXG[NP][520];
    __shared__ __align__(16) float sFeat[NP][260];
    __shared__ __align__(16) float sH[16][132];
    __shared__ float sEmit[2][32];

    const int tid = threadIdx.x;
    const int b  = blockIdx.x >> 5;
    const int i0 = (blockIdx.x & 31) * TI;
    const int lens_b = lens[b];

    // ---- stage feats: wave covers one full row (perfectly coalesced) ----
    for (int idx = tid; idx < NP * 64; idx += 256) {
        const int p  = idx >> 6;
        const int k4 = (idx & 63) << 2;
        const int gp = i0 + p;
        float4 v = make_float4(0.f, 0.f, 0.f, 0.f);
        if (gp < LL) v = *(const float4*)(feats + ((size_t)b * LL + gp) * HH + k4);
        *(float4*)(&sFeat[p][k4]) = v;
    }
    __syncthreads();

    const int lane = tid & 63, wv = tid >> 6;
    const int m = lane & 15, q = lane >> 4;

    // ---- phase 1: sXG[p][g] = sum_k sFeat[p][k] * WihT[k][g] + (b_ih+b_hh)[g]
    // wave wv owns gates [128wv,128wv+128); lane: g0 = 128wv+8m (16 lanes x 32B = 512B
    // contiguous, q-duplicate lanes merge); p0 = 5q (sFeat reads conflict-free, pad 260).
    {
        const int g0 = wv * 128 + m * 8;
        const int p0 = q * 5;
        float bsum[8];
        {
            float4 a0 = *(const float4*)(b_ih + g0);
            float4 a1 = *(const float4*)(b_ih + g0 + 4);
            float4 c0 = *(const float4*)(b_hh + g0);
            float4 c1 = *(const float4*)(b_hh + g0 + 4);
            bsum[0]=a0.x+c0.x; bsum[1]=a0.y+c0.y; bsum[2]=a0.z+c0.z; bsum[3]=a0.w+c0.w;
            bsum[4]=a1.x+c1.x; bsum[5]=a1.y+c1.y; bsum[6]=a1.z+c1.z; bsum[7]=a1.w+c1.w;
        }
        float acc[5][8];
        #pragma unroll
        for (int pi = 0; pi < 5; ++pi)
            #pragma unroll
            for (int gi = 0; gi < 8; ++gi) acc[pi][gi] = 0.f;

        for (int k = 0; k < HH; k += 4) {
            float w[4][8];
            #pragma unroll
            for (int kk = 0; kk < 4; ++kk) {
                const float4 w0 = *(const float4*)(WihT + (size_t)(k + kk) * NG + g0);
                const float4 w1 = *(const float4*)(WihT + (size_t)(k + kk) * NG + g0 + 4);
                w[kk][0]=w0.x; w[kk][1]=w0.y; w[kk][2]=w0.z; w[kk][3]=w0.w;
                w[kk][4]=w1.x; w[kk][5]=w1.y; w[kk][6]=w1.z; w[kk][7]=w1.w;
            }
            #pragma unroll
            for (int pi = 0; pi < 5; ++pi) {
                const float4 f = *(const float4*)(&sFeat[p0 + pi][k]);
                const float fr[4] = {f.x, f.y, f.z, f.w};
                #pragma unroll
                for (int kk = 0; kk < 4; ++kk)
                    #pragma unroll
                    for (int gi = 0; gi < 8; ++gi)
                        acc[pi][gi] += fr[kk] * w[kk][gi];
            }
        }
        #pragma unroll
        for (int pi = 0; pi < 5; ++pi) {
            float4 o0 = make_float4(acc[pi][0]+bsum[0], acc[pi][1]+bsum[1],
                                    acc[pi][2]+bsum[2], acc[pi][3]+bsum[3]);
            float4 o1 = make_float4(acc[pi][4]+bsum[4], acc[pi][5]+bsum[5],
                                    acc[pi][6]+bsum[6], acc[pi][7]+bsum[7]);
            *(float4*)(&sXG[p0 + pi][g0])     = o0;
            *(float4*)(&sXG[p0 + pi][g0 + 4]) = o1;
        }
    }
    __syncthreads();

    // ---- phase 2: 4-step recurrence. Thread owns (j0,j0+1) x all 4 gate types x 4 seqs
    // -> cell computed in-register, no gate exchange. Wave wv owns j in [32wv,32wv+32)
    // (W_hhT reads: 16 lanes x 8B contiguous per tau, q-duplicates merge).
    const int j0 = 32 * wv + 2 * m;
    const int s0 = 4 * q;
    float c[4][2];
    #pragma unroll
    for (int si = 0; si < 4; ++si) { c[si][0] = 0.f; c[si][1] = 0.f; }

    for (int t = 0; t < 4; ++t) {
        float acc[4][4][2];   // [si][tau][jj]  gate pre-activations
        #pragma unroll
        for (int si = 0; si < 4; ++si)
            #pragma unroll
            for (int ta = 0; ta < 4; ++ta) {
                const float2 g2 = *(const float2*)(&sXG[s0 + si + t][ta * HD + j0]);
                acc[si][ta][0] = g2.x; acc[si][ta][1] = g2.y;
            }
        if (t > 0) {
            for (int k = 0; k < HD; k += 4) {
                float w[4][4][2];
                #pragma unroll
                for (int kk = 0; kk < 4; ++kk)
                    #pragma unroll
                    for (int ta = 0; ta < 4; ++ta) {
                        const float2 w2 = *(const float2*)(WhhT + (size_t)(k + kk) * NG + ta * HD + j0);
                        w[kk][ta][0] = w2.x; w[kk][ta][1] = w2.y;
                    }
                #pragma unroll
                for (int si = 0; si < 4; ++si) {
                    const float4 h4 = *(const float4*)(&sH[s0 + si][k]);   // broadcast/2-way
                    const float hr[4] = {h4.x, h4.y, h4.z, h4.w};
                    #pragma unroll
                    for (int kk = 0; kk < 4; ++kk)
                        #pragma unroll
                        for (int ta = 0; ta < 4; ++ta) {
                            acc[si][ta][0] += hr[kk] * w[kk][ta][0];
                            acc[si][ta][1] += hr[kk] * w[kk][ta][1];
                        }
                }
            }
        }
        __syncthreads();   // all reads of old sH done

        #pragma unroll
        for (int si = 0; si < 4; ++si) {
            float2 hv;
            {
                const float ig = sigm(acc[si][0][0]);
                const float fg = sigm(acc[si][1][0]);
                const float gg = tanhf_(acc[si][2][0]);
                const float og = sigm(acc[si][3][0]);
                c[si][0] = fg * c[si][0] + ig * gg;
                hv.x = og * tanhf_(c[si][0]);
            }
            {
                const float ig = sigm(acc[si][0][1]);
                const float fg = sigm(acc[si][1][1]);
                const float gg = tanhf_(acc[si][2][1]);
                const float og = sigm(acc[si][3][1]);
                c[si][1] = fg * c[si][1] + ig * gg;
                hv.y = og * tanhf_(c[si][1]);
            }
            *(float2*)(&sH[s0 + si][j0]) = hv;   // 2-way banked, free
        }
        __syncthreads();   // new sH visible

        // ---- emission for spans whose selected step == t+1 ----
        if (tid < 128) {   // waves 0,1 entirely (wave-uniform branch)
            const int es = tid & 15, etag = (tid >> 4) & 1, ekc = tid >> 5;
            float part = 0.f;
            #pragma unroll
            for (int jj = 0; jj < 8; ++jj) {
                const float4 hv = *(const float4*)(&sH[es][ekc * 32 + 4 * jj]);
                const float4 wt = *(const float4*)(W_tri + (size_t)etag * HD + ekc * 32 + 4 * jj);
                part += hv.x*wt.x + hv.y*wt.y + hv.z*wt.z + hv.w*wt.w;
            }
            part += __shfl_down(part, 32);
            if ((tid & 32) == 0) sEmit[tid >> 6][tid & 31] = part;
        }
        __syncthreads();
        if (tid < 32) {
            const int es = tid & 15, etag = tid >> 4;
            const int i = i0 + es;
            const int rem = lens_b - i;
            const int sc = t + 1;
            if (rem > 0 && sc <= rem) {
                const float e = sEmit[0][tid] + sEmit[1][tid] + b_tri[etag];
                const int mm  = rem < 4 ? rem : 4;
                const int whi = (sc >= mm) ? 4 : sc;
                for (int w2 = sc; w2 <= whi; ++w2) {
                    const int jj2 = i + w2 - 1;
                    if (jj2 < LL)
                        out[(((size_t)b * LL + i) * LL + jj2) * 2 + etag] = e;
                }
            }
        }
    }
}

// ---------------- fallback (round-1 kernel) if ws too small for transposes ----------------
__global__ __launch_bounds__(256, 2) void fused_span_lstm_v1(
    const float* __restrict__ feats, const float* __restrict__ W_ih,
    const float* __restrict__ W_hh, const float* __restrict__ b_ih,
    const float* __restrict__ b_hh, const float* __restrict__ W_tri,
    const float* __restrict__ b_tri, const int* __restrict__ lens,
    float* __restrict__ out)
{
    __shared__ __align__(16) float sFeat[NP][HH];
    __shared__ __align__(16) float sXG[NP][4 * HD];
    __shared__ __align__(16) float sH[TI][HD];

    const int tid = threadIdx.x;
    const int b  = blockIdx.x >> 5;
    const int i0 = (blockIdx.x & 31) * TI;
    const int lens_b = lens[b];

    for (int idx = tid; idx < NP * HH; idx += 256) {
        const int p = idx >> 8;
        const int k = idx & (HH - 1);
        const int gp = i0 + p;
        sFeat[p][k] = (gp < LL) ? feats[((size_t)b * LL + gp) * HH + k] : 0.0f;
    }
    for (int idx = tid; idx < TI * HD; idx += 256) ((float*)sH)[idx] = 0.0f;
    __syncthreads();

    {
        const int g0 = (tid & 63) * 8;
        const int pb = (tid >> 6) * 5;
        float acc[5][8];
        #pragma unroll
        for (int pi = 0; pi < 5; ++pi)
            #pragma unroll
            for (int gi = 0; gi < 8; ++gi) acc[pi][gi] = 0.0f;
        for (int kk = 0; kk < HH; kk += 4) {
            float4 wvv[8];
            #pragma unroll
            for (int gi = 0; gi < 8; ++gi)
                wvv[gi] = *(const float4*)(W_ih + (size_t)(g0 + gi) * HH + kk);
            #pragma unroll
            for (int pi = 0; pi < 5; ++pi) {
                const float4 f = *(const float4*)(&sFeat[pb + pi][kk]);
                #pragma unroll
                for (int gi = 0; gi < 8; ++gi)
                    acc[pi][gi] += wvv[gi].x * f.x + wvv[gi].y * f.y
                                 + wvv[gi].z * f.z + wvv[gi].w * f.w;
            }
        }
        float bsum[8];
        #pragma unroll
        for (int gi = 0; gi < 8; ++gi) bsum[gi] = b_ih[g0 + gi] + b_hh[g0 + gi];
        #pragma unroll
        for (int pi = 0; pi < 5; ++pi)
            #pragma unroll
            for (int gi = 0; gi < 8; ++gi)
                sXG[pb + pi][g0 + gi] = acc[pi][gi] + bsum[gi];
    }
    __syncthreads();

    const int j  = tid & (HD - 1);
    const int sg = tid >> 7;
    float c[8];
    #pragma unroll
    for (int si = 0; si < 8; ++si) c[si] = 0.0f;

    for (int t = 0; t < 4; ++t) {
        float acc2[8][4];
        #pragma unroll
        for (int si = 0; si < 8; ++si) {
            const int s = sg * 8 + si;
            #pragma unroll
            for (int g = 0; g < 4; ++g)
                acc2[si][g] = sXG[s + t][g * HD + j];
        }
        for (int kk = 0; kk < HD; kk += 4) {
            float4 wvv[4];
            #pragma unroll
            for (int g = 0; g < 4; ++g)
                wvv[g] = *(const float4*)(W_hh + (size_t)(g * HD + j) * HD + kk);
            #pragma unroll
            for (int si = 0; si < 8; ++si) {
                const float4 hv = *(const float4*)(&sH[sg * 8 + si][kk]);
                #pragma unroll
                for (int g = 0; g < 4; ++g)
                    acc2[si][g] += wvv[g].x * hv.x + wvv[g].y * hv.y
                                 + wvv[g].z * hv.z + wvv[g].w * hv.w;
            }
        }
        __syncthreads();
        float hnew[8];
        #pragma unroll
        for (int si = 0; si < 8; ++si) {
            const float ig = sigm(acc2[si][0]);
            const float fg = sigm(acc2[si][1]);
            const float gg = tanhf_(acc2[si][2]);
            const float og = sigm(acc2[si][3]);
            c[si]   = fg * c[si] + ig * gg;
            hnew[si] = og * tanhf_(c[si]);
        }
        #pragma unroll
        for (int si = 0; si < 8; ++si) sH[sg * 8 + si][j] = hnew[si];
        __syncthreads();

        if (tid < 32) {
            const int s = tid >> 1, tag = tid & 1;
            const int i = i0 + s;
            const int rem = lens_b - i;
            const int sc = t + 1;
            if (rem > 0 && sc <= rem) {
                float ex = 0.f;
                for (int kk = 0; kk < HD; kk += 4) {
                    const float4 hv = *(const float4*)(&sH[s][kk]);
                    const float4 wt = *(const float4*)(W_tri + (size_t)tag * HD + kk);
                    ex += hv.x*wt.x + hv.y*wt.y + hv.z*wt.z + hv.w*wt.w;
                }
                const float e = ex + b_tri[tag];
                const int mmm = rem < 4 ? rem : 4;
                const int whi = (sc >= mmm) ? 4 : sc;
                for (int w = sc; w <= whi; ++w) {
                    const int jj = i + w - 1;
                    if (jj < LL)
                        out[(((size_t)b * LL + i) * LL + jj) * 2 + tag] = e;
                }
            }
        }
    }
}

extern "C" void kernel_launch(void* const* d_in, const int* in_sizes, int n_in,
                              void* d_out, int out_size, void* d_ws, size_t ws_size,
                              hipStream_t stream)
{
    const float* feats = (const float*)d_in[0];
    const float* W_ih  = (const float*)d_in[1];
    const float* W_hh  = (const float*)d_in[2];
    const float* b_ih  = (const float*)d_in[3];
    const float* b_hh  = (const float*)d_in[4];
    const float* W_tri = (const float*)d_in[5];
    const float* b_tri = (const float*)d_in[6];
    const int*   lens  = (const int*)d_in[7];
    float* out = (float*)d_out;

    hipMemsetAsync(out, 0, (size_t)out_size * sizeof(float), stream);

    const size_t need = (size_t)(NG * HH + NG * HD) * sizeof(float);  // 768 KB
    if (ws_size >= need) {
        float* WihT = (float*)d_ws;
        float* WhhT = WihT + NG * HH;
        transpose_w<<<(NG * HH + NG * HD) / 256, 256, 0, stream>>>(W_ih, W_hh, WihT, WhhT);
        span_lstm_v2<<<NB * (LL / TI), 256, 0, stream>>>(feats, WihT, WhhT, b_ih, b_hh,
                                                         W_tri, b_tri, lens, out);
    } else {
        fused_span_lstm_v1<<<NB * (LL / TI), 256, 0, stream>>>(feats, W_ih, W_hh, b_ih, b_hh,
                                                               W_tri, b_tri, lens, out);
    }
}

// Round 3
// 292.343 us; speedup vs baseline: 6.6760x; 2.2718x over previous
//
#include <hip/hip_runtime.h>
#include <cstddef>

#define NB 64
#define LL 512
#define HH 256
#define HD 128
#define NG 512
#define TI 16

typedef _Float16 half_t;
typedef _Float16 half8 __attribute__((ext_vector_type(8)));
typedef _Float16 half4 __attribute__((ext_vector_type(4)));
typedef float f32x4 __attribute__((ext_vector_type(4)));

#define MFMA16(a, b, c) __builtin_amdgcn_mfma_f32_16x16x32_f16((a), (b), (c), 0, 0, 0)

// LDS pitches (chosen for <=2-way bank aliasing, which is free on CDNA4)
#define FP 264   // sFeatb pitch (f16): 528 B -> 132 dw -> 4*row%32 -> 2-way on b128
#define XP 522   // sXG pitch (f32): 2088 B -> 8*row%32 -> 2-way on 4B r/w
#define HFP 132  // sHf pitch (f32)
#define HBP 136  // sHb pitch (f16): 272 B -> 68 dw -> 4*row%32 -> 2-way on b128

__device__ __forceinline__ float sigm(float x)  { return 1.0f / (1.0f + __expf(-x)); }
__device__ __forceinline__ float tanhf_(float x){ return 2.0f / (1.0f + __expf(-2.0f * x)) - 1.0f; }

// ---- prep: cast weights to f16 (row-major [g][k] == B-fragment-friendly), bsum = b_ih+b_hh ----
__global__ void prep_weights(const float* __restrict__ Wih, const float* __restrict__ Whh,
                             const float* __restrict__ bih, const float* __restrict__ bhh,
                             half_t* __restrict__ WihH, half_t* __restrict__ WhhH,
                             float* __restrict__ bsum)
{
    const int idx = blockIdx.x * 256 + threadIdx.x;
    if (idx < NG * HH) WihH[idx] = (half_t)Wih[idx];
    if (idx < NG * HD) WhhH[idx] = (half_t)Whh[idx];
    if (idx < NG)      bsum[idx] = bih[idx] + bhh[idx];
}

__global__ __launch_bounds__(256, 2) void span_lstm_mfma(
    const float* __restrict__ feats, const half_t* __restrict__ WihH,
    const half_t* __restrict__ WhhH, const float* __restrict__ bsum,
    const float* __restrict__ W_tri, const float* __restrict__ b_tri,
    const int* __restrict__ lens, float* __restrict__ out)
{
    // LDS: 16896 + 41760 + 8448 + 4352 + 256 = 71712 B -> 2 blocks/CU
    __shared__ __align__(16) half_t sFeatb[32 * FP];   // rows 20..31 uninit (only D rows 16..19 stored)
    __shared__ __align__(16) float  sXG[20 * XP];
    __shared__ __align__(16) float  sHf[16 * HFP];
    __shared__ __align__(16) half_t sHb[16 * HBP];
    __shared__ float sEmit[2][32];

    const int tid = threadIdx.x;
    const int b  = blockIdx.x >> 5;
    const int i0 = (blockIdx.x & 31) * TI;
    const int lens_b = lens[b];

    // ---- stage feats window as f16 (coalesced float4 global reads) ----
    for (int idx = tid; idx < 20 * 64; idx += 256) {
        const int p  = idx >> 6;
        const int k4 = (idx & 63) << 2;
        const int gp = i0 + p;
        float4 v = make_float4(0.f, 0.f, 0.f, 0.f);
        if (gp < LL) v = *(const float4*)(feats + ((size_t)b * LL + gp) * HH + k4);
        half4 hv = {(half_t)v.x, (half_t)v.y, (half_t)v.z, (half_t)v.w};
        *(half4*)(&sFeatb[p * FP + k4]) = hv;
    }
    __syncthreads();

    const int lane = tid & 63, wv = tid >> 6;
    const int lm = lane & 15;          // m / n within 16-tile
    const int lq = lane >> 4;          // quad

    // ---- phase 1 (MFMA): XG[p][g] = sum_k F[p][k] * Wih[g][k] + bsum[g] ----
    {
        // A-frags: 2 M-tiles x 8 K-frags, from LDS
        half8 afr[2][8];
        #pragma unroll
        for (int mt = 0; mt < 2; ++mt)
            #pragma unroll
            for (int kf = 0; kf < 8; ++kf)
                afr[mt][kf] = *(const half8*)(&sFeatb[(16 * mt + lm) * FP + kf * 32 + lq * 8]);

        const int gwv = wv * 128;
        for (int nt = 0; nt < 8; ++nt) {
            const int gb = gwv + nt * 16;
            const float bs = bsum[gb + lm];
            f32x4 acc0 = {0.f, 0.f, 0.f, 0.f}, acc1 = {0.f, 0.f, 0.f, 0.f};
            #pragma unroll
            for (int kf = 0; kf < 8; ++kf) {
                const half8 bfr = *(const half8*)(WihH + (size_t)(gb + lm) * HH + kf * 32 + lq * 8);
                acc0 = MFMA16(afr[0][kf], bfr, acc0);
                acc1 = MFMA16(afr[1][kf], bfr, acc1);
            }
            // D: row p = 16*mt + 4*lq + r, col gb+lm. Store only p < 20.
            #pragma unroll
            for (int r = 0; r < 4; ++r)
                sXG[(lq * 4 + r) * XP + gb + lm] = acc0[r] + bs;
            if (lq == 0) {
                #pragma unroll
                for (int r = 0; r < 4; ++r)
                    sXG[(16 + r) * XP + gb + lm] = acc1[r] + bs;
            }
        }
    }

    // ---- phase 2 B-frags: Whh, held in registers across all steps ----
    // wave wv owns j in [32wv, 32wv+32): tiles (jt in {0,1}) x (ta = gate type 0..3)
    const int j0 = 32 * wv;
    half8 bf2[2][4][4];
    #pragma unroll
    for (int jt = 0; jt < 2; ++jt)
        #pragma unroll
        for (int ta = 0; ta < 4; ++ta)
            #pragma unroll
            for (int kf = 0; kf < 4; ++kf)
                bf2[jt][ta][kf] = *(const half8*)(WhhH + (size_t)(ta * HD + j0 + jt * 16 + lm) * HD
                                                  + kf * 32 + lq * 8);
    __syncthreads();   // sXG visible to all

    float cc[2][4] = {{0.f, 0.f, 0.f, 0.f}, {0.f, 0.f, 0.f, 0.f}};

    for (int t = 0; t < 4; ++t) {
        float accg[2][4][4];   // [jt][ta][r]
        if (t > 0) {
            half8 ah[4];
            #pragma unroll
            for (int kf = 0; kf < 4; ++kf)
                ah[kf] = *(const half8*)(&sHb[lm * HBP + kf * 32 + lq * 8]);
            #pragma unroll
            for (int jt = 0; jt < 2; ++jt)
                #pragma unroll
                for (int ta = 0; ta < 4; ++ta) {
                    f32x4 a = {0.f, 0.f, 0.f, 0.f};
                    #pragma unroll
                    for (int kf = 0; kf < 4; ++kf)
                        a = MFMA16(ah[kf], bf2[jt][ta][kf], a);
                    #pragma unroll
                    for (int r = 0; r < 4; ++r) accg[jt][ta][r] = a[r];
                }
        } else {
            #pragma unroll
            for (int jt = 0; jt < 2; ++jt)
                #pragma unroll
                for (int ta = 0; ta < 4; ++ta)
                    #pragma unroll
                    for (int r = 0; r < 4; ++r) accg[jt][ta][r] = 0.f;
        }
        // + XG (row s+t, col ta*128 + j)
        #pragma unroll
        for (int jt = 0; jt < 2; ++jt)
            #pragma unroll
            for (int ta = 0; ta < 4; ++ta)
                #pragma unroll
                for (int r = 0; r < 4; ++r)
                    accg[jt][ta][r] += sXG[(lq * 4 + r + t) * XP + ta * HD + j0 + jt * 16 + lm];

        // cell update (fully in-lane)
        float hh[2][4];
        #pragma unroll
        for (int jt = 0; jt < 2; ++jt)
            #pragma unroll
            for (int r = 0; r < 4; ++r) {
                const float ig = sigm(accg[jt][0][r]);
                const float fg = sigm(accg[jt][1][r]);
                const float gg = tanhf_(accg[jt][2][r]);
                const float og = sigm(accg[jt][3][r]);
                cc[jt][r] = fg * cc[jt][r] + ig * gg;
                hh[jt][r] = og * tanhf_(cc[jt][r]);
            }
        __syncthreads();   // all A-frag reads of old sHb complete
        #pragma unroll
        for (int jt = 0; jt < 2; ++jt)
            #pragma unroll
            for (int r = 0; r < 4; ++r) {
                const int s = lq * 4 + r, j = j0 + jt * 16 + lm;
                sHf[s * HFP + j] = hh[jt][r];
                sHb[s * HBP + j] = (half_t)hh[jt][r];
            }
        __syncthreads();   // new sHf/sHb visible

        // ---- emission for spans whose selected step == t+1 (fp32 path) ----
        if (tid < 128) {
            const int es = tid & 15, etag = (tid >> 4) & 1, ekc = tid >> 5;
            float part = 0.f;
            #pragma unroll
            for (int jj = 0; jj < 8; ++jj) {
                const float4 hv = *(const float4*)(&sHf[es * HFP + ekc * 32 + 4 * jj]);
                const float4 wt = *(const float4*)(W_tri + (size_t)etag * HD + ekc * 32 + 4 * jj);
                part += hv.x * wt.x + hv.y * wt.y + hv.z * wt.z + hv.w * wt.w;
            }
            part += __shfl_down(part, 32);
            if ((tid & 32) == 0) sEmit[tid >> 6][tid & 31] = part;
        }
        __syncthreads();
        if (tid < 32) {
            const int es = tid & 15, etag = tid >> 4;
            const int i = i0 + es;
            const int rem = lens_b - i;
            const int sc = t + 1;
            if (rem > 0 && sc <= rem) {
                const float e = sEmit[0][tid] + sEmit[1][tid] + b_tri[etag];
                const int mm  = rem < 4 ? rem : 4;
                const int whi = (sc >= mm) ? 4 : sc;
                for (int w2 = sc; w2 <= whi; ++w2) {
                    const int jj2 = i + w2 - 1;
                    if (jj2 < LL)
                        out[(((size_t)b * LL + i) * LL + jj2) * 2 + etag] = e;
                }
            }
        }
    }
}

extern "C" void kernel_launch(void* const* d_in, const int* in_sizes, int n_in,
                              void* d_out, int out_size, void* d_ws, size_t ws_size,
                              hipStream_t stream)
{
    const float* feats = (const float*)d_in[0];
    const float* W_ih  = (const float*)d_in[1];
    const float* W_hh  = (const float*)d_in[2];
    const float* b_ih  = (const float*)d_in[3];
    const float* b_hh  = (const float*)d_in[4];
    const float* W_tri = (const float*)d_in[5];
    const float* b_tri = (const float*)d_in[6];
    const int*   lens  = (const int*)d_in[7];
    float* out = (float*)d_out;

    hipMemsetAsync(out, 0, (size_t)out_size * sizeof(float), stream);

    // ws layout: WihH (256 KB) | WhhH (128 KB) | bsum (2 KB)  -- total ~395 KB
    half_t* WihH = (half_t*)d_ws;
    half_t* WhhH = WihH + (size_t)NG * HH;
    float*  bsum = (float*)(WhhH + (size_t)NG * HD);

    prep_weights<<<(NG * HH + 255) / 256, 256, 0, stream>>>(W_ih, W_hh, b_ih, b_hh,
                                                            WihH, WhhH, bsum);
    span_lstm_mfma<<<NB * (LL / TI), 256, 0, stream>>>(feats, WihH, WhhH, bsum,
                                                       W_tri, b_tri, lens, out);
}